// Round 4
// baseline (99.188 us; speedup 1.0000x reference)
//
#include <hip/hip_runtime.h>
#include <math.h>

#define IMG_W 512
#define IMG_H 512
#define RPT 16
#define STRIPS (IMG_H / RPT)   // 32 strips per column
#define XG (IMG_W / 4)         // 128 x-groups (4 px per thread)

struct Row { float d[4], t[4], s[4]; };   // d=R-L, s=L+C+R, t=s+C per pixel

__device__ __forceinline__ void load_row(const float* __restrict__ img, int y, int x0, Row& w) {
    if ((unsigned)y >= (unsigned)IMG_H) {
#pragma unroll
        for (int j = 0; j < 4; ++j) { w.d[j] = 0.f; w.t[j] = 0.f; w.s[j] = 0.f; }
        return;
    }
    const float* row = img + (size_t)y * IMG_W;
    const float4 c = *(const float4*)(row + x0);
    const float l = (x0 > 0)           ? row[x0 - 1] : 0.f;
    const float r = (x0 + 4 < IMG_W)   ? row[x0 + 4] : 0.f;
    const float L[4] = {l,   c.x, c.y, c.z};
    const float C[4] = {c.x, c.y, c.z, c.w};
    const float R[4] = {c.y, c.z, c.w, r};
#pragma unroll
    for (int j = 0; j < 4; ++j) {
        w.d[j] = R[j] - L[j];
        const float lr = L[j] + R[j];
        w.s[j] = lr + C[j];
        w.t[j] = w.s[j] + C[j];
    }
}

__global__ __launch_bounds__(256) void loss_partial_kernel(
        const float* __restrict__ pred, const float* __restrict__ targ,
        float* __restrict__ partial) {
    const int tid   = blockIdx.x * 256 + threadIdx.x;
    const int g     = tid & (XG - 1);
    const int rest  = tid >> 7;               // / XG
    const int strip = rest & (STRIPS - 1);
    const int b     = rest >> 5;              // / STRIPS
    const int x0    = g * 4;
    const float* p = pred + (size_t)b * IMG_H * IMG_W;
    const float* t = targ + (size_t)b * IMG_H * IMG_W;
    const int y0 = strip * RPT;

    const float eps2 = 0.001f * 0.001f;

    Row pa, pb, pc, ta, tb, tc;
    load_row(p, y0 - 1, x0, pa);
    load_row(p, y0,     x0, pb);
    load_row(t, y0 - 1, x0, ta);
    load_row(t, y0,     x0, tb);

    float sum = 0.f;
#pragma unroll
    for (int i = 0; i < RPT; ++i) {
        load_row(p, y0 + i + 1, x0, pc);
        load_row(t, y0 + i + 1, x0, tc);
#pragma unroll
        for (int j = 0; j < 4; ++j) {
            const float sxp = pa.d[j] + 2.f * pb.d[j] + pc.d[j];
            const float syp = pc.t[j] - pa.t[j];
            const float lpp = 9.f * (pb.t[j] - pb.s[j]) - (pa.s[j] + pb.s[j] + pc.s[j]);

            const float sxt = ta.d[j] + 2.f * tb.d[j] + tc.d[j];
            const float syt = tc.t[j] - ta.t[j];
            const float lpt = 9.f * (tb.t[j] - tb.s[j]) - (ta.s[j] + tb.s[j] + tc.s[j]);

            const float ax = fabsf(sxp) * __expf(-10.f * fabsf(sxt));
            const float ay = fabsf(syp) * __expf(-10.f * fabsf(syt));
            const float al = fabsf(lpp) * __expf(-10.f * fabsf(lpt));

            const float cx = sqrtf(fmaf(ax, ax, eps2));
            const float cy = sqrtf(fmaf(ay, ay, eps2));
            const float cl = sqrtf(fmaf(al, al, eps2));

            sum += 10.f * (cx + cy) + cl;
        }
        pa = pb; pb = pc;
        ta = tb; tb = tc;
    }

    // wave (64-lane) reduce, then block reduce
#pragma unroll
    for (int off = 32; off > 0; off >>= 1) sum += __shfl_down(sum, off, 64);
    __shared__ float ws[4];
    const int lane = threadIdx.x & 63, wid = threadIdx.x >> 6;
    if (lane == 0) ws[wid] = sum;
    __syncthreads();
    if (threadIdx.x == 0) partial[blockIdx.x] = ws[0] + ws[1] + ws[2] + ws[3];
}

__global__ __launch_bounds__(256) void loss_final_kernel(
        const float* __restrict__ partial, int n, float* __restrict__ out, float scale) {
    float s = 0.f;
    for (int i = threadIdx.x; i < n; i += 256) s += partial[i];
#pragma unroll
    for (int off = 32; off > 0; off >>= 1) s += __shfl_down(s, off, 64);
    __shared__ float ws[4];
    const int lane = threadIdx.x & 63, wid = threadIdx.x >> 6;
    if (lane == 0) ws[wid] = s;
    __syncthreads();
    if (threadIdx.x == 0) out[0] = (ws[0] + ws[1] + ws[2] + ws[3]) * scale;
}

extern "C" void kernel_launch(void* const* d_in, const int* in_sizes, int n_in,
                              void* d_out, int out_size, void* d_ws, size_t ws_size,
                              hipStream_t stream) {
    const float* pred = (const float*)d_in[0];
    const float* targ = (const float*)d_in[1];
    float* out = (float*)d_out;
    float* partial = (float*)d_ws;

    const int total = in_sizes[0];                        // 64*512*512
    const int B = total / (IMG_H * IMG_W);                // 64
    const int nthreads = B * STRIPS * XG;                 // 262144
    const int nblocks = nthreads / 256;                   // 1024

    loss_partial_kernel<<<nblocks, 256, 0, stream>>>(pred, targ, partial);
    const float scale = 1.0f / (float)total;
    loss_final_kernel<<<1, 256, 0, stream>>>(partial, nblocks, out, scale);
}

// Round 5
// 64.642 us; speedup vs baseline: 1.5344x; 1.5344x over previous
//
#include <hip/hip_runtime.h>
#include <math.h>

#define IMG_W 512
#define IMG_H 512
#define RPT 8
#define STRIPS (IMG_H / RPT)   // 64 strips per column
#define PX 2                   // pixels per thread
#define XG (IMG_W / PX)        // 256 x-groups == blockDim.x

// Per-row factorized quantities for PX pixels: d=R-L, s=L+C+R, t=s+C.
// sobel_x = d_a + 2 d_b + d_c ; sobel_y = t_c - t_a ; lap = 9(t_b - s_b) - (s_a+s_b+s_c)
struct Row { float d[PX], t[PX], s[PX]; };

__device__ __forceinline__ void load_row(const float* __restrict__ img, int y, int x0, Row& w) {
    if ((unsigned)y >= (unsigned)IMG_H) {
#pragma unroll
        for (int j = 0; j < PX; ++j) { w.d[j] = 0.f; w.t[j] = 0.f; w.s[j] = 0.f; }
        return;
    }
    const float* row = img + (size_t)y * IMG_W;
    const float2 c = *(const float2*)(row + x0);
    const float l = (x0 > 0)          ? row[x0 - 1]  : 0.f;
    const float r = (x0 + PX < IMG_W) ? row[x0 + PX] : 0.f;
    // j=0: (L,C,R) = (l,   c.x, c.y)   j=1: (L,C,R) = (c.x, c.y, r)
    w.d[0] = c.y - l;
    w.s[0] = l + c.x + c.y;
    w.t[0] = w.s[0] + c.x;
    w.d[1] = r - c.x;
    w.s[1] = c.x + c.y + r;
    w.t[1] = w.s[1] + c.y;
}

__global__ __launch_bounds__(256, 4) void loss_partial_kernel(
        const float* __restrict__ pred, const float* __restrict__ targ,
        float* __restrict__ partial) {
    // One block = one (batch, strip) pair; threadIdx.x = x-group.
    const int strip = blockIdx.x & (STRIPS - 1);
    const int b     = blockIdx.x >> 6;          // / STRIPS
    const int x0    = threadIdx.x * PX;
    const float* p = pred + (size_t)b * IMG_H * IMG_W;
    const float* t = targ + (size_t)b * IMG_H * IMG_W;
    const int y0 = strip * RPT;

    const float eps2 = 0.001f * 0.001f;

    Row pa, pb, pc, ta, tb, tc;
    load_row(p, y0 - 1, x0, pa);
    load_row(p, y0,     x0, pb);
    load_row(t, y0 - 1, x0, ta);
    load_row(t, y0,     x0, tb);

    float sumXY = 0.f, sumL = 0.f;
#pragma unroll 2
    for (int i = 0; i < RPT; ++i) {
        load_row(p, y0 + i + 1, x0, pc);
        load_row(t, y0 + i + 1, x0, tc);
#pragma unroll
        for (int j = 0; j < PX; ++j) {
            const float sxp = fmaf(2.f, pb.d[j], pa.d[j]) + pc.d[j];
            const float syp = pc.t[j] - pa.t[j];
            const float lpp = fmaf(9.f, pb.t[j] - pb.s[j], -(pa.s[j] + pb.s[j] + pc.s[j]));

            const float sxt = fmaf(2.f, tb.d[j], ta.d[j]) + tc.d[j];
            const float syt = tc.t[j] - ta.t[j];
            const float lpt = fmaf(9.f, tb.t[j] - tb.s[j], -(ta.s[j] + tb.s[j] + tc.s[j]));

            const float ax = fabsf(sxp) * __expf(-10.f * fabsf(sxt));
            const float ay = fabsf(syp) * __expf(-10.f * fabsf(syt));
            const float al = fabsf(lpp) * __expf(-10.f * fabsf(lpt));

            sumXY += sqrtf(fmaf(ax, ax, eps2)) + sqrtf(fmaf(ay, ay, eps2));
            sumL  += sqrtf(fmaf(al, al, eps2));
        }
        pa = pb; pb = pc;
        ta = tb; tb = tc;
    }

    float sum = fmaf(10.f, sumXY, sumL);

    // wave (64-lane) reduce, then block reduce
#pragma unroll
    for (int off = 32; off > 0; off >>= 1) sum += __shfl_down(sum, off, 64);
    __shared__ float ws[4];
    const int lane = threadIdx.x & 63, wid = threadIdx.x >> 6;
    if (lane == 0) ws[wid] = sum;
    __syncthreads();
    if (threadIdx.x == 0) partial[blockIdx.x] = ws[0] + ws[1] + ws[2] + ws[3];
}

__global__ __launch_bounds__(256) void loss_final_kernel(
        const float* __restrict__ partial, int n, float* __restrict__ out, float scale) {
    float s = 0.f;
    for (int i = threadIdx.x; i < n; i += 256) s += partial[i];
#pragma unroll
    for (int off = 32; off > 0; off >>= 1) s += __shfl_down(s, off, 64);
    __shared__ float ws[4];
    const int lane = threadIdx.x & 63, wid = threadIdx.x >> 6;
    if (lane == 0) ws[wid] = s;
    __syncthreads();
    if (threadIdx.x == 0) out[0] = (ws[0] + ws[1] + ws[2] + ws[3]) * scale;
}

extern "C" void kernel_launch(void* const* d_in, const int* in_sizes, int n_in,
                              void* d_out, int out_size, void* d_ws, size_t ws_size,
                              hipStream_t stream) {
    const float* pred = (const float*)d_in[0];
    const float* targ = (const float*)d_in[1];
    float* out = (float*)d_out;
    float* partial = (float*)d_ws;

    const int total = in_sizes[0];                 // 64*512*512
    const int B = total / (IMG_H * IMG_W);         // 64
    const int nblocks = B * STRIPS;                // 4096 (256 threads each)

    loss_partial_kernel<<<nblocks, 256, 0, stream>>>(pred, targ, partial);
    const float scale = 1.0f / (float)total;
    loss_final_kernel<<<1, 256, 0, stream>>>(partial, nblocks, out, scale);
}

// Round 6
// 43.148 us; speedup vs baseline: 2.2988x; 1.4982x over previous
//
#include <hip/hip_runtime.h>
#include <math.h>

#define IMG_W 512
#define IMG_H 512
#define RPT 8
#define STRIPS (IMG_H / RPT)     // 64 strips per image
#define IMG_PX (IMG_H * IMG_W)   // 262144

#if __has_builtin(__builtin_amdgcn_exp2f)
#define EXP2F(x) __builtin_amdgcn_exp2f(x)
#else
#define EXP2F(x) exp2f(x)
#endif
#if __has_builtin(__builtin_amdgcn_sqrtf)
#define SQRTF(x) __builtin_amdgcn_sqrtf(x)
#else
#define SQRTF(x) sqrtf(x)
#endif

// -10 * log2(e): exp(-10*z) = exp2(-14.4269504*z)
#define NEG10_LOG2E (-14.426950408889634f)

// Per-row factorized taps for 2 pixels. d=R-L, s=L+C+R, t=s+C.
// sobel_x = d_a + 2 d_b + d_c ; sobel_y = t_c - t_a ; lap = 9(t_b-s_b) - (s_a+s_b+s_c)
struct Rw { float d0, t0, s0, d1, t1, s1; };

__device__ __forceinline__ void row_dst(const float* __restrict__ base, int idxc, int y,
                                        bool eL, bool eR, Rw& w) {
    if ((unsigned)y < (unsigned)IMG_H) {   // wave-uniform branch
        // quad = (L0, C0, C1, R1) at flat elements idxc..idxc+3 (4B-aligned dwordx4)
        const float4 v = *(const float4*)(base + idxc);
        const float L0 = eL ? 0.f : v.x;
        const float R1 = eR ? 0.f : v.w;
        w.d0 = v.z - L0;
        w.s0 = L0 + v.y + v.z;
        w.t0 = w.s0 + v.y;
        w.d1 = R1 - v.y;
        w.s1 = v.y + v.z + R1;
        w.t1 = w.s1 + v.z;
    } else {
        w.d0 = w.t0 = w.s0 = w.d1 = w.t1 = w.s1 = 0.f;
    }
}

__global__ __launch_bounds__(256, 4) void loss_partial_kernel(
        const float* __restrict__ pred, const float* __restrict__ targ,
        float* __restrict__ partial, int nimg) {
    const int strip = blockIdx.x & (STRIPS - 1);
    const int b     = blockIdx.x >> 6;           // / STRIPS
    const int x0    = threadIdx.x << 1;          // 0..510 (2 px per thread)
    const int y0    = strip * RPT;
    const bool eL = (x0 == 0);
    const bool eR = (x0 == IMG_W - 2);
    const int nmax = nimg * IMG_PX - 4;          // last safe dwordx4 start

    // flat element index of (b, y, x0-1); walk by +IMG_W per row
    int idx = b * IMG_PX + (y0 - 1) * IMG_W + (x0 - 1);

    const float eps2 = 1e-6f;

    Rw pa, pb, pc, ta, tb, tc;
    {
        int ic = min(max(idx, 0), nmax);
        row_dst(pred, ic, y0 - 1, eL, eR, pa);
        row_dst(targ, ic, y0 - 1, eL, eR, ta);
        idx += IMG_W;
        ic = min(max(idx, 0), nmax);
        row_dst(pred, ic, y0, eL, eR, pb);
        row_dst(targ, ic, y0, eL, eR, tb);
        idx += IMG_W;
    }

    float sXY = 0.f, sL = 0.f;
#pragma unroll
    for (int i = 0; i < RPT; ++i) {
        const int ic = min(max(idx, 0), nmax);
        const int y = y0 + i + 1;
        row_dst(pred, ic, y, eL, eR, pc);
        row_dst(targ, ic, y, eL, eR, tc);
        idx += IMG_W;

        {   // pixel 0
            const float sxp = fmaf(2.f, pb.d0, pa.d0) + pc.d0;
            const float syp = pc.t0 - pa.t0;
            const float lpp = fmaf(9.f, pb.t0 - pb.s0, -(pa.s0 + pb.s0 + pc.s0));
            const float sxt = fmaf(2.f, tb.d0, ta.d0) + tc.d0;
            const float syt = tc.t0 - ta.t0;
            const float lpt = fmaf(9.f, tb.t0 - tb.s0, -(ta.s0 + tb.s0 + tc.s0));
            const float ax = fabsf(sxp) * EXP2F(fabsf(sxt) * NEG10_LOG2E);
            const float ay = fabsf(syp) * EXP2F(fabsf(syt) * NEG10_LOG2E);
            const float al = fabsf(lpp) * EXP2F(fabsf(lpt) * NEG10_LOG2E);
            sXY += SQRTF(fmaf(ax, ax, eps2)) + SQRTF(fmaf(ay, ay, eps2));
            sL  += SQRTF(fmaf(al, al, eps2));
        }
        {   // pixel 1
            const float sxp = fmaf(2.f, pb.d1, pa.d1) + pc.d1;
            const float syp = pc.t1 - pa.t1;
            const float lpp = fmaf(9.f, pb.t1 - pb.s1, -(pa.s1 + pb.s1 + pc.s1));
            const float sxt = fmaf(2.f, tb.d1, ta.d1) + tc.d1;
            const float syt = tc.t1 - ta.t1;
            const float lpt = fmaf(9.f, tb.t1 - tb.s1, -(ta.s1 + tb.s1 + tc.s1));
            const float ax = fabsf(sxp) * EXP2F(fabsf(sxt) * NEG10_LOG2E);
            const float ay = fabsf(syp) * EXP2F(fabsf(syt) * NEG10_LOG2E);
            const float al = fabsf(lpp) * EXP2F(fabsf(lpt) * NEG10_LOG2E);
            sXY += SQRTF(fmaf(ax, ax, eps2)) + SQRTF(fmaf(ay, ay, eps2));
            sL  += SQRTF(fmaf(al, al, eps2));
        }
        pa = pb; pb = pc;   // full unroll -> register renaming, no movs
        ta = tb; tb = tc;
    }

    float sum = fmaf(10.f, sXY, sL);

    // wave (64-lane) reduce, then block reduce
#pragma unroll
    for (int off = 32; off > 0; off >>= 1) sum += __shfl_down(sum, off, 64);
    __shared__ float ws[4];
    const int lane = threadIdx.x & 63, wid = threadIdx.x >> 6;
    if (lane == 0) ws[wid] = sum;
    __syncthreads();
    if (threadIdx.x == 0) partial[blockIdx.x] = ws[0] + ws[1] + ws[2] + ws[3];
}

__global__ __launch_bounds__(256) void loss_final_kernel(
        const float* __restrict__ partial, int n, float* __restrict__ out, float scale) {
    float s = 0.f;
    for (int i = threadIdx.x; i < n; i += 256) s += partial[i];
#pragma unroll
    for (int off = 32; off > 0; off >>= 1) s += __shfl_down(s, off, 64);
    __shared__ float ws[4];
    const int lane = threadIdx.x & 63, wid = threadIdx.x >> 6;
    if (lane == 0) ws[wid] = s;
    __syncthreads();
    if (threadIdx.x == 0) out[0] = (ws[0] + ws[1] + ws[2] + ws[3]) * scale;
}

extern "C" void kernel_launch(void* const* d_in, const int* in_sizes, int n_in,
                              void* d_out, int out_size, void* d_ws, size_t ws_size,
                              hipStream_t stream) {
    const float* pred = (const float*)d_in[0];
    const float* targ = (const float*)d_in[1];
    float* out = (float*)d_out;
    float* partial = (float*)d_ws;

    const int total = in_sizes[0];                 // 64*512*512
    const int B = total / (IMG_H * IMG_W);         // 64
    const int nblocks = B * STRIPS;                // 4096

    loss_partial_kernel<<<nblocks, 256, 0, stream>>>(pred, targ, partial, B);
    const float scale = 1.0f / (float)total;
    loss_final_kernel<<<1, 256, 0, stream>>>(partial, nblocks, out, scale);
}

// Round 8
// 37.938 us; speedup vs baseline: 2.6145x; 1.1373x over previous
//
#include <hip/hip_runtime.h>
#include <math.h>

#define IMG_W 512
#define IMG_H 512
#define RPT 8
#define STRIPS (IMG_H / RPT)     // 64 strips per image
#define IMG_PX (IMG_H * IMG_W)   // 262144

#if __has_builtin(__builtin_amdgcn_exp2f)
#define EXP2F(x) __builtin_amdgcn_exp2f(x)
#else
#define EXP2F(x) exp2f(x)
#endif
#if __has_builtin(__builtin_amdgcn_sqrtf)
#define SQRTF(x) __builtin_amdgcn_sqrtf(x)
#else
#define SQRTF(x) sqrtf(x)
#endif

// exp(-10*z) = exp2(-14.4269504*z)
#define NEG10_LOG2E (-14.426950408889634f)

// Per-row factorized taps for 2 pixels. d=R-L, s=L+C+R, t=s+C.
// sobel_x = d_a + 2 d_b + d_c ; sobel_y = t_c - t_a ; lap = 9(t_b-s_b) - (s_a+s_b+s_c)
struct Rw { float d0, t0, s0, d1, t1, s1; };

__device__ __forceinline__ Rw make_dst(float4 v, bool eL, bool eR) {
    Rw w;
    const float L0 = eL ? 0.f : v.x;   // quad = (x0-1, x0, x0+1, x0+2)
    const float R1 = eR ? 0.f : v.w;
    w.d0 = v.z - L0;
    w.s0 = L0 + v.y + v.z;
    w.t0 = w.s0 + v.y;
    w.d1 = R1 - v.y;
    w.s1 = v.y + v.z + R1;
    w.t1 = w.s1 + v.z;
    return w;
}

__device__ __forceinline__ Rw zero_dst() {
    Rw w; w.d0 = w.t0 = w.s0 = w.d1 = w.t1 = w.s1 = 0.f; return w;
}

__global__ __launch_bounds__(256, 4) void loss_partial_kernel(
        const float* __restrict__ pred, const float* __restrict__ targ,
        float* __restrict__ partial, int nimg) {
    const int strip = blockIdx.x & (STRIPS - 1);
    const int b     = blockIdx.x >> 6;           // / STRIPS
    const int x0    = threadIdx.x << 1;          // 0..510 (2 px per thread)
    const int y0    = strip * RPT;
    const bool eL = (x0 == 0);
    const bool eR = (x0 == IMG_W - 2);
    const int nmax = nimg * IMG_PX - 4;          // last safe dwordx4 start

    // flat element index of (b, y0, x0-1); rows step by IMG_W
    const int rowIdx = b * IMG_PX + y0 * IMG_W + (x0 - 1);

    const float eps2 = 1e-6f;

    Rw pa, pb, ta, tb;
    if (strip == 0) {                 // y0-1 == -1 -> zero row, no load
        pa = zero_dst(); ta = zero_dst();
    } else {
        pa = make_dst(*(const float4*)(pred + rowIdx - IMG_W), eL, eR);
        ta = make_dst(*(const float4*)(targ + rowIdx - IMG_W), eL, eR);
    }
    {
        const int ic = max(rowIdx, 0);           // only b=0,strip=0,x0=0 hits -1
        pb = make_dst(*(const float4*)(pred + ic), eL, eR);
        tb = make_dst(*(const float4*)(targ + ic), eL, eR);
    }

    // raw quads for row y0+1 (always a valid row: y0+1 <= 505)
    float4 rp = *(const float4*)(pred + rowIdx + IMG_W);
    float4 rt = *(const float4*)(targ + rowIdx + IMG_W);

    const bool lastStrip = (strip == STRIPS - 1);

    float sXY = 0.f, sL = 0.f;
#pragma unroll
    for (int i = 0; i < RPT; ++i) {
        // prefetch raw quads for row y0+i+2 (skip on last iter: never consumed)
        float4 rp2, rt2;
        if (i < RPT - 1) {
            const int ip = min(rowIdx + (i + 2) * IMG_W, nmax);  // clamp for strip 63
            rp2 = *(const float4*)(pred + ip);
            rt2 = *(const float4*)(targ + ip);
        }

        // convert raw row y0+i+1 -> window row c (zero if beyond image: last iter of strip 63)
        Rw pc, tc;
        if (i == RPT - 1 && lastStrip) {
            pc = zero_dst(); tc = zero_dst();
        } else {
            pc = make_dst(rp, eL, eR);
            tc = make_dst(rt, eL, eR);
        }

        {   // pixel 0
            const float sxp = fmaf(2.f, pb.d0, pa.d0) + pc.d0;
            const float syp = pc.t0 - pa.t0;
            const float lpp = fmaf(9.f, pb.t0 - pb.s0, -(pa.s0 + pb.s0 + pc.s0));
            const float sxt = fmaf(2.f, tb.d0, ta.d0) + tc.d0;
            const float syt = tc.t0 - ta.t0;
            const float lpt = fmaf(9.f, tb.t0 - tb.s0, -(ta.s0 + tb.s0 + tc.s0));
            const float ax = fabsf(sxp) * EXP2F(fabsf(sxt) * NEG10_LOG2E);
            const float ay = fabsf(syp) * EXP2F(fabsf(syt) * NEG10_LOG2E);
            const float al = fabsf(lpp) * EXP2F(fabsf(lpt) * NEG10_LOG2E);
            sXY += SQRTF(fmaf(ax, ax, eps2)) + SQRTF(fmaf(ay, ay, eps2));
            sL  += SQRTF(fmaf(al, al, eps2));
        }
        {   // pixel 1
            const float sxp = fmaf(2.f, pb.d1, pa.d1) + pc.d1;
            const float syp = pc.t1 - pa.t1;
            const float lpp = fmaf(9.f, pb.t1 - pb.s1, -(pa.s1 + pb.s1 + pc.s1));
            const float sxt = fmaf(2.f, tb.d1, ta.d1) + tc.d1;
            const float syt = tc.t1 - ta.t1;
            const float lpt = fmaf(9.f, tb.t1 - tb.s1, -(ta.s1 + tb.s1 + tc.s1));
            const float ax = fabsf(sxp) * EXP2F(fabsf(sxt) * NEG10_LOG2E);
            const float ay = fabsf(syp) * EXP2F(fabsf(syt) * NEG10_LOG2E);
            const float al = fabsf(lpp) * EXP2F(fabsf(lpt) * NEG10_LOG2E);
            sXY += SQRTF(fmaf(ax, ax, eps2)) + SQRTF(fmaf(ay, ay, eps2));
            sL  += SQRTF(fmaf(al, al, eps2));
        }

        pa = pb; pb = pc;      // full unroll -> register renaming
        ta = tb; tb = tc;
        rp = rp2; rt = rt2;
    }

    float sum = fmaf(10.f, sXY, sL);

    // wave (64-lane) reduce, then block reduce
#pragma unroll
    for (int off = 32; off > 0; off >>= 1) sum += __shfl_down(sum, off, 64);
    __shared__ float ws[4];
    const int lane = threadIdx.x & 63, wid = threadIdx.x >> 6;
    if (lane == 0) ws[wid] = sum;
    __syncthreads();
    if (threadIdx.x == 0) partial[blockIdx.x] = ws[0] + ws[1] + ws[2] + ws[3];
}

__global__ __launch_bounds__(256) void loss_final_kernel(
        const float* __restrict__ partial, int n, float* __restrict__ out, float scale) {
    float s = 0.f;
    for (int i = threadIdx.x; i < n; i += 256) s += partial[i];
#pragma unroll
    for (int off = 32; off > 0; off >>= 1) s += __shfl_down(s, off, 64);
    __shared__ float ws[4];
    const int lane = threadIdx.x & 63, wid = threadIdx.x >> 6;
    if (lane == 0) ws[wid] = s;
    __syncthreads();
    if (threadIdx.x == 0) out[0] = (ws[0] + ws[1] + ws[2] + ws[3]) * scale;
}

extern "C" void kernel_launch(void* const* d_in, const int* in_sizes, int n_in,
                              void* d_out, int out_size, void* d_ws, size_t ws_size,
                              hipStream_t stream) {
    const float* pred = (const float*)d_in[0];
    const float* targ = (const float*)d_in[1];
    float* out = (float*)d_out;
    float* partial = (float*)d_ws;

    const int total = in_sizes[0];                 // 64*512*512
    const int B = total / (IMG_H * IMG_W);         // 64
    const int nblocks = B * STRIPS;                // 4096

    loss_partial_kernel<<<nblocks, 256, 0, stream>>>(pred, targ, partial, B);
    const float scale = 1.0f / (float)total;
    loss_final_kernel<<<1, 256, 0, stream>>>(partial, nblocks, out, scale);
}